// Round 1
// baseline (405.647 us; speedup 1.0000x reference)
//
#include <hip/hip_runtime.h>
#include <math.h>

// Problem constants
#define B_   32
#define CD   1280     // C
#define HW_  1024
#define TD_  768
#define LD_  64
#define EPSF 1e-5f
#define LORA_SCALE_F 0.125f   // 64^-0.5

// ---------- reduction helpers ----------
__device__ __forceinline__ float wredSum(float a) {
#pragma unroll
  for (int o = 32; o; o >>= 1) a += __shfl_xor(a, o, 64);
  return a;
}
__device__ __forceinline__ void wred2(float& a, float& b) {
#pragma unroll
  for (int o = 32; o; o >>= 1) { a += __shfl_xor(a, o, 64); b += __shfl_xor(b, o, 64); }
}
// block of 256 threads
__device__ __forceinline__ float blockSum(float v, float* red) {
  int t = threadIdx.x;
  red[t] = v; __syncthreads();
#pragma unroll
  for (int s = 128; s > 0; s >>= 1) { if (t < s) red[t] += red[t + s]; __syncthreads(); }
  float r = red[0]; __syncthreads();
  return r;
}
__device__ __forceinline__ float blockMax(float v, float* red) {
  int t = threadIdx.x;
  red[t] = v; __syncthreads();
#pragma unroll
  for (int s = 128; s > 0; s >>= 1) { if (t < s) red[t] = fmaxf(red[t], red[t + s]); __syncthreads(); }
  float r = red[0]; __syncthreads();
  return r;
}
__device__ __forceinline__ void blockSum2(float& a, float& b, float2* red) {
  int t = threadIdx.x;
  red[t] = make_float2(a, b); __syncthreads();
#pragma unroll
  for (int s = 128; s > 0; s >>= 1) {
    if (t < s) { red[t].x += red[t + s].x; red[t].y += red[t + s].y; }
    __syncthreads();
  }
  a = red[0].x; b = red[0].y; __syncthreads();
}

// ---------- A12: q[c] = to_q_w[c,:] . LN(token_q_emb)*g+b ; grid 320x256 ----------
__global__ __launch_bounds__(256) void kA12(const float* __restrict__ tq,
                                            const float* __restrict__ lng,
                                            const float* __restrict__ lnb,
                                            const float* __restrict__ to_q_w,
                                            float* __restrict__ q_out) {
  __shared__ float lnq[TD_];
  __shared__ float2 red[256];
  int t = threadIdx.x;
  float s = 0.f, ss = 0.f, vals[3];
#pragma unroll
  for (int k = 0; k < 3; k++) { float v = tq[t + 256 * k]; vals[k] = v; s += v; ss += v * v; }
  blockSum2(s, ss, red);
  float mu = s * (1.f / TD_);
  float r = rsqrtf(ss * (1.f / TD_) - mu * mu + EPSF);
#pragma unroll
  for (int k = 0; k < 3; k++) { int i = t + 256 * k; lnq[i] = (vals[k] - mu) * r * lng[i] + lnb[i]; }
  __syncthreads();
  int c = blockIdx.x * 4 + (t >> 6);
  int lane = t & 63;
  const float4* w4 = (const float4*)(to_q_w + (size_t)c * TD_);
  const float4* l4 = (const float4*)lnq;
  float dot = 0.f;
#pragma unroll
  for (int i = 0; i < 3; i++) {
    int f = i * 64 + lane;
    float4 w = w4[f], l = l4[f];
    dot += w.x * l.x + w.y * l.y + w.z * l.z + w.w * l.w;
  }
  dot = wredSum(dot);
  if (lane == 0) q_out[c] = dot;
}

// ---------- A34: lora_q[d] = lora_q_w[d,:] . LN(q) ; grid 16x256 ----------
__global__ __launch_bounds__(256) void kA34(const float* __restrict__ q_in,
                                            const float* __restrict__ lora_q_w,
                                            float* __restrict__ lq_out) {
  __shared__ float qs[CD];
  __shared__ float2 red[256];
  int t = threadIdx.x;
  float s = 0.f, ss = 0.f, vals[5];
#pragma unroll
  for (int k = 0; k < 5; k++) { float v = q_in[t + 256 * k]; vals[k] = v; s += v; ss += v * v; }
  blockSum2(s, ss, red);
  float mu = s * (1.f / CD);
  float r = rsqrtf(ss * (1.f / CD) - mu * mu + EPSF);
#pragma unroll
  for (int k = 0; k < 5; k++) { int i = t + 256 * k; qs[i] = (vals[k] - mu) * r; }
  __syncthreads();
  int d = blockIdx.x * 4 + (t >> 6);
  int lane = t & 63;
  const float4* w4 = (const float4*)(lora_q_w + (size_t)d * CD);
  const float4* q4 = (const float4*)qs;
  float dot = 0.f;
#pragma unroll
  for (int i = 0; i < 5; i++) {
    int f = i * 64 + lane;
    float4 w = w4[f], qq = q4[f];
    dot += w.x * qq.x + w.y * qq.y + w.z * qq.z + w.w * qq.w;
  }
  dot = wredSum(dot);
  if (lane == 0) lq_out[d] = dot;
}

// ---------- A56: w_eff[c] = sum_d lora_q[d]*lora_k_w[d,c] ; grid 5x256 ----------
__global__ __launch_bounds__(256) void kA56(const float* __restrict__ lq,
                                            const float* __restrict__ lora_k_w,
                                            float* __restrict__ w_eff) {
  __shared__ float l[LD_];
  int t = threadIdx.x;
  if (t < LD_) l[t] = lq[t];
  __syncthreads();
  int c = blockIdx.x * 256 + t;
  float acc = 0.f;
#pragma unroll 8
  for (int d = 0; d < LD_; d++) acc += l[d] * lora_k_w[(size_t)d * CD + c];
  w_eff[c] = acc;
}

// ---------- B: sim[row] from inquery (double-LN + dot) ; grid 2048x256 ----------
__global__ __launch_bounds__(256) void kB(const float* __restrict__ kin,
                                          const float* __restrict__ g,
                                          const float* __restrict__ bb,
                                          const float* __restrict__ w_eff,
                                          float* __restrict__ sim) {
  __shared__ float4 gs[CD / 4], bs[CD / 4], ws[CD / 4];
  __shared__ float red[256];
  int t = threadIdx.x;
  float wsum = 0.f;
  for (int k = t; k < CD / 4; k += 256) {
    float4 w = ((const float4*)w_eff)[k];
    ws[k] = w;
    gs[k] = ((const float4*)g)[k];
    bs[k] = ((const float4*)bb)[k];
    wsum += w.x + w.y + w.z + w.w;
  }
  float W0 = blockSum(wsum, red);
  int wid = t >> 6, lane = t & 63;
  int gw = blockIdx.x * 4 + wid;
  for (int row = gw; row < B_ * HW_; row += 8192) {
    const float4* x4 = (const float4*)(kin + (size_t)row * CD);
    float4 xv[5];
    float s = 0.f, ss = 0.f;
#pragma unroll
    for (int i = 0; i < 5; i++) {
      float4 v = x4[i * 64 + lane];
      xv[i] = v;
      s += v.x + v.y + v.z + v.w;
      ss += v.x * v.x + v.y * v.y + v.z * v.z + v.w * v.w;
    }
    wred2(s, ss);
    float mu1 = s * (1.f / CD);
    float r1 = rsqrtf(ss * (1.f / CD) - mu1 * mu1 + EPSF);
    float s2 = 0.f, ss2 = 0.f;
#pragma unroll
    for (int i = 0; i < 5; i++) {
      int f = i * 64 + lane;
      float4 G = gs[f], Bv = bs[f], v = xv[i], kk;
      kk.x = (v.x - mu1) * r1 * G.x + Bv.x;
      kk.y = (v.y - mu1) * r1 * G.y + Bv.y;
      kk.z = (v.z - mu1) * r1 * G.z + Bv.z;
      kk.w = (v.w - mu1) * r1 * G.w + Bv.w;
      xv[i] = kk;
      s2 += kk.x + kk.y + kk.z + kk.w;
      ss2 += kk.x * kk.x + kk.y * kk.y + kk.z * kk.z + kk.w * kk.w;
    }
    wred2(s2, ss2);
    float mu2 = s2 * (1.f / CD);
    float r2 = rsqrtf(ss2 * (1.f / CD) - mu2 * mu2 + EPSF);
    float dot = 0.f;
#pragma unroll
    for (int i = 0; i < 5; i++) {
      float4 w = ws[i * 64 + lane], kk = xv[i];
      dot += w.x * kk.x + w.y * kk.y + w.z * kk.z + w.w * kk.w;
    }
    dot = wredSum(dot);
    if (lane == 0) sim[row] = LORA_SCALE_F * r2 * (dot - mu2 * W0);
  }
}

// ---------- D1: per-column (b,j) stats of infeat ; grid 512x256 ----------
__global__ __launch_bounds__(256) void kD1(const float* __restrict__ infeat,
                                           float* __restrict__ mu_out,
                                           float* __restrict__ r_out) {
  int tile = blockIdx.x & 15, b = blockIdx.x >> 4;
  int t = threadIdx.x;
  int jg = t & 15;      // 16 float4 groups -> 64 columns
  int slice = t >> 4;   // 16 c-slices of 80
  int j0 = tile * 64 + jg * 4;
  const float* base = infeat + (size_t)b * CD * HW_ + j0;
  float4 s = make_float4(0, 0, 0, 0), q = make_float4(0, 0, 0, 0);
  int c0 = slice * 80;
#pragma unroll 4
  for (int c = c0; c < c0 + 80; c++) {
    float4 v = *(const float4*)(base + (size_t)c * HW_);
    s.x += v.x; s.y += v.y; s.z += v.z; s.w += v.w;
    q.x += v.x * v.x; q.y += v.y * v.y; q.z += v.z * v.z; q.w += v.w * v.w;
  }
  __shared__ float4 sArr[16][16], qArr[16][16];
  sArr[slice][jg] = s; qArr[slice][jg] = q;
  __syncthreads();
#pragma unroll
  for (int st = 8; st > 0; st >>= 1) {
    if (slice < st) {
      float4 a = sArr[slice][jg], b2 = sArr[slice + st][jg];
      a.x += b2.x; a.y += b2.y; a.z += b2.z; a.w += b2.w;
      sArr[slice][jg] = a;
      a = qArr[slice][jg]; b2 = qArr[slice + st][jg];
      a.x += b2.x; a.y += b2.y; a.z += b2.z; a.w += b2.w;
      qArr[slice][jg] = a;
    }
    __syncthreads();
  }
  if (slice == 0) {
    float4 S = sArr[0][jg], Q = qArr[0][jg], mu, r;
    mu.x = S.x * (1.f / CD); mu.y = S.y * (1.f / CD);
    mu.z = S.z * (1.f / CD); mu.w = S.w * (1.f / CD);
    r.x = rsqrtf(Q.x * (1.f / CD) - mu.x * mu.x + EPSF);
    r.y = rsqrtf(Q.y * (1.f / CD) - mu.y * mu.y + EPSF);
    r.z = rsqrtf(Q.z * (1.f / CD) - mu.z * mu.z + EPSF);
    r.w = rsqrtf(Q.w * (1.f / CD) - mu.w * mu.w + EPSF);
    int j = b * HW_ + j0;
    *(float4*)(mu_out + j) = mu;
    *(float4*)(r_out + j) = r;
  }
}

// ---------- C: softmax + weight folding ; grid 32x256 ----------
__global__ __launch_bounds__(256) void kC(const float* __restrict__ sim,
                                          const float* __restrict__ mask,
                                          const float* __restrict__ mu,
                                          const float* __restrict__ r,
                                          float* __restrict__ w1,
                                          float* __restrict__ w2,
                                          float* __restrict__ S1,
                                          float* __restrict__ S3) {
  __shared__ float red[256];
  __shared__ float2 red2[256];
  int b = blockIdx.x, t = threadIdx.x;
  float4 sv = ((const float4*)(sim + b * HW_))[t];
  float4 mv = ((const float4*)(mask + b * HW_))[t];
  float4 muv = ((const float4*)(mu + b * HW_))[t];
  float4 rv = ((const float4*)(r + b * HW_))[t];
  const float NEG = -3.4028235e38f;
  float se0 = mv.x > 0.f ? sv.x : NEG;
  float se1 = mv.y > 0.f ? sv.y : NEG;
  float se2 = mv.z > 0.f ? sv.z : NEG;
  float se3 = mv.w > 0.f ? sv.w : NEG;
  float m = fmaxf(fmaxf(se0, se1), fmaxf(se2, se3));
  float M = blockMax(m, red);
  float e0 = expf(se0 - M), e1 = expf(se1 - M), e2 = expf(se2 - M), e3 = expf(se3 - M);
  float Z = blockSum(e0 + e1 + e2 + e3, red);
  float inv = 1.f / Z;
  float a0 = e0 * inv, a1 = e1 * inv, a2 = e2 * inv, a3 = e3 * inv;
  float4 w1v = make_float4(a0 * rv.x, a1 * rv.y, a2 * rv.z, a3 * rv.w);
  float4 w2v = make_float4(rv.x * (1.f / HW_), rv.y * (1.f / HW_),
                           rv.z * (1.f / HW_), rv.w * (1.f / HW_));
  float s1 = w1v.x * muv.x + w1v.y * muv.y + w1v.z * muv.z + w1v.w * muv.w;
  float s3 = w2v.x * muv.x + w2v.y * muv.y + w2v.z * muv.z + w2v.w * muv.w;
  blockSum2(s1, s3, red2);
  ((float4*)(w1 + b * HW_))[t] = w1v;
  ((float4*)(w2 + b * HW_))[t] = w2v;
  if (t == 0) { S1[b] = s1; S3[b] = s3; }
}

// ---------- D2: out = [fg, bg] via weighted row dots over infeat ; grid 1280x256 ----------
__global__ __launch_bounds__(256) void kD2(const float* __restrict__ infeat,
                                           const float* __restrict__ w1,
                                           const float* __restrict__ w2,
                                           const float* __restrict__ S1,
                                           const float* __restrict__ S3,
                                           const float* __restrict__ g,
                                           const float* __restrict__ bb,
                                           float* __restrict__ out) {
  __shared__ float4 w1s[HW_ / 4], w2s[HW_ / 4];
  int t = threadIdx.x;
  int b = blockIdx.x / 40, tile = blockIdx.x % 40;
  w1s[t] = ((const float4*)(w1 + b * HW_))[t];
  w2s[t] = ((const float4*)(w2 + b * HW_))[t];
  __syncthreads();
  int wid = t >> 6, lane = t & 63;
  float s1 = S1[b], s3 = S3[b];
#pragma unroll
  for (int k = 0; k < 8; k++) {
    int c = tile * 32 + wid * 8 + k;
    const float4* x4 = (const float4*)(infeat + (size_t)b * CD * HW_ + (size_t)c * HW_);
    float d1 = 0.f, d2 = 0.f;
#pragma unroll
    for (int i = 0; i < 4; i++) {
      int f = i * 64 + lane;
      float4 x = x4[f], a = w1s[f], w = w2s[f];
      d1 += x.x * a.x + x.y * a.y + x.z * a.z + x.w * a.w;
      d2 += x.x * w.x + x.y * w.y + x.z * w.z + x.w * w.w;
    }
    wred2(d1, d2);
    if (lane == 0) {
      float gc = g[c], bc = bb[c];
      float fg = gc * (d1 - s1) + bc;
      float vm = gc * (d2 - s3) + bc;
      out[(size_t)b * (2 * CD) + c] = fg;
      out[(size_t)b * (2 * CD) + CD + c] = vm - fg;
    }
  }
}

extern "C" void kernel_launch(void* const* d_in, const int* in_sizes, int n_in,
                              void* d_out, int out_size, void* d_ws, size_t ws_size,
                              hipStream_t stream) {
  const float* infeat  = (const float*)d_in[0];
  const float* inquery = (const float*)d_in[1];
  const float* tq      = (const float*)d_in[2];
  const float* to_q_w  = (const float*)d_in[3];
  const float* ln_x_g  = (const float*)d_in[4];
  const float* ln_x_b  = (const float*)d_in[5];
  const float* ln_k_g  = (const float*)d_in[6];
  const float* ln_k_b  = (const float*)d_in[7];
  const float* ln_q_g  = (const float*)d_in[8];
  const float* ln_q_b  = (const float*)d_in[9];
  const float* lora_q_w = (const float*)d_in[10];
  const float* lora_k_w = (const float*)d_in[11];
  const float* mask    = (const float*)d_in[12];
  float* out = (float*)d_out;

  float* ws = (float*)d_ws;
  float* q_ws    = ws;              // 1280
  float* lq_ws   = ws + 1280;       // 64
  float* weff_ws = ws + 1344;       // 1280
  float* sim_ws  = ws + 2624;       // 32768
  float* mu_ws   = ws + 35392;      // 32768
  float* r_ws    = ws + 68160;      // 32768
  float* w1_ws   = ws + 100928;     // 32768
  float* w2_ws   = ws + 133696;     // 32768
  float* S1_ws   = ws + 166464;     // 32
  float* S3_ws   = ws + 166496;     // 32

  kA12<<<320, 256, 0, stream>>>(tq, ln_q_g, ln_q_b, to_q_w, q_ws);
  kA34<<<16, 256, 0, stream>>>(q_ws, lora_q_w, lq_ws);
  kA56<<<5, 256, 0, stream>>>(lq_ws, lora_k_w, weff_ws);
  kB<<<2048, 256, 0, stream>>>(inquery, ln_k_g, ln_k_b, weff_ws, sim_ws);
  kD1<<<512, 256, 0, stream>>>(infeat, mu_ws, r_ws);
  kC<<<32, 256, 0, stream>>>(sim_ws, mask, mu_ws, r_ws, w1_ws, w2_ws, S1_ws, S3_ws);
  kD2<<<1280, 256, 0, stream>>>(infeat, w1_ws, w2_ws, S1_ws, S3_ws, ln_x_g, ln_x_b, out);
}